// Round 12
// baseline (44.758 us; speedup 1.0000x reference)
//
#include <hip/hip_runtime.h>
#include <math.h>

#define B_ 32
#define P_ 1000
#define T_ 16
#define D_ 78
#define O_ 72
#define NXB 16            // p-chunks of 64
#define BIGC 100000000.0f

// ---------------- K1: masked-L1 sums S + per-p scalars + per-block partial maxes ----------------
// Stores only S[b][t][p] (dist = S/clen and liou = (30c-S)/(30c+S+1e-9) are both
// recomputable bit-identically in k2 from S + cnt). Also zeroes the k2 completion
// counters (runs before k2 in the graph each replay).
__global__ __launch_bounds__(1024, 8) void k1(
        const float* __restrict__ preds, const float* __restrict__ targets,
        const int* __restrict__ imgw_p, const int* __restrict__ imgh_p,
        float* __restrict__ Sarr, float4* __restrict__ scal4, float* __restrict__ pths,
        float* __restrict__ pmax, float* __restrict__ cntg, int* __restrict__ ctr) {
    __shared__ float pred_s[64 * 81];
    __shared__ float2 tomg[T_ * O_];
    __shared__ float Spart[T_][4][64];
    __shared__ float wmax[16][3];
    __shared__ float cnt_s[T_], clen_s[T_], ts0_s[T_], ts1_s[T_], tth_s[T_];

    const int b = blockIdx.y, bx = blockIdx.x;
    const int p0 = bx * 64;
    const int rows = min(64, P_ - p0);
    const int tid = threadIdx.x;
    const float w = (float)(imgw_p[0] - 1);
    const float h = (float)(imgh_p[0] - 1);
    const float imgwf = (float)imgw_p[0];

    {
        const float4* gbase = (const float4*)(preds + ((size_t)b * P_ + p0) * D_);
        const int n4 = rows * D_ / 4;
        for (int i = tid; i < n4; i += 1024) {
            float4 v = gbase[i];
            int base = i * 4;
            int r = base / D_, c = base - r * D_;
#pragma unroll
            for (int k = 0; k < 4; ++k) {
                int cc = c + k, rr = r;
                if (cc >= D_) { cc -= D_; ++rr; }
                float x = (&v.x)[k];
                if (cc >= 6 || cc == 3) x *= w;
                pred_s[rr * 81 + cc] = x;
            }
        }
    }
    for (int i = tid; i < T_ * O_; i += 1024) {
        int t = i / O_, o = i - t * O_;
        float to = targets[((size_t)b * T_ + t) * D_ + 6 + o] * w;
        float m = (to >= 0.f && to < imgwf) ? 1.f : 0.f;
        tomg[((t >> 2) * O_ + o) * 4 + (t & 3)] = make_float2(to, m);
    }
    __syncthreads();
    if (tid < T_) {
        int t = tid;
        float c = 0.f;
        for (int o = 0; o < O_; ++o) c += tomg[((t >> 2) * O_ + o) * 4 + (t & 3)].y;
        cnt_s[t] = c;
        clen_s[t] = fmaxf(c, 1.f);
        const float* tr = targets + ((size_t)b * T_ + t) * D_;
        ts0_s[t] = tr[2] * h;
        ts1_s[t] = tr[3] * w;
        tth_s[t] = tr[4];
    }
    __syncthreads();

    // export cnt + zero the per-batch completion counter (bx==0 blocks only)
    if (bx == 0) {
        if (tid < T_) cntg[b * T_ + tid] = cnt_s[tid];
        if (tid == 32) ctr[b] = 0;
    }

    {
        const int lane = tid & 63;
        const int wv = tid >> 6;
        const int tg = wv & 3;
        const int oq = wv >> 2;
        const float* lrow = pred_s + lane * 81;
        const float4* tg4 = (const float4*)(tomg + (size_t)tg * O_ * 4);
        const int o_lo = oq * 18;
        float S0 = 0.f, S1 = 0.f, S2 = 0.f, S3 = 0.f;
#pragma unroll
        for (int i = 0; i < 18; ++i) {
            int o = o_lo + i;
            float po = lrow[6 + o];
            float4 r0 = tg4[2 * o];
            float4 r1 = tg4[2 * o + 1];
            S0 += r0.y * fabsf(po - r0.x);
            S1 += r0.w * fabsf(po - r0.z);
            S2 += r1.y * fabsf(po - r1.x);
            S3 += r1.w * fabsf(po - r1.z);
        }
        Spart[4 * tg + 0][oq][lane] = S0;
        Spart[4 * tg + 1][oq][lane] = S1;
        Spart[4 * tg + 2][oq][lane] = S2;
        Spart[4 * tg + 3][oq][lane] = S3;
    }
    __syncthreads();

    const int th = tid >> 6, pl = tid & 63;
    const int p = p0 + pl;
    float ldm = 0.f, lsm = 0.f, ltm = 0.f;
    if (pl < rows) {
        float S = ((Spart[th][0][pl] + Spart[th][1][pl]) + Spart[th][2][pl]) + Spart[th][3][pl];
        Sarr[(size_t)(b * T_ + th) * P_ + p] = S;
        float dv = S / clen_s[th];          // needed only for the dist-max
        ldm = dv;
        const float* prow = pred_s + pl * 81;
        float ps0 = prow[2] * h, ps1 = prow[3], pth = prow[4];
        float d0 = ps0 - ts0_s[th], d1 = ps1 - ts1_s[th];
        lsm = sqrtf(d0 * d0 + d1 * d1);
        ltm = fabsf(pth - tth_s[th]) * 180.f;
        if (th == 0) {
            float fc[2];
#pragma unroll
            for (int c = 0; c < 2; ++c) {
                float x = prow[c];
                float pc = 1.f / (1.f + expf(-x));
                float neg = -logf(1.f - pc + 1e-12f) * 0.75f * pc * pc;
                float pos = -logf(pc + 1e-12f) * 0.25f * (1.f - pc) * (1.f - pc);
                fc[c] = pos - neg;
            }
            scal4[(size_t)b * P_ + p] = make_float4(fc[0], fc[1], ps0, ps1);
            pths[(size_t)b * P_ + p] = pth;
        }
    }

    for (int off = 32; off; off >>= 1) {
        ldm = fmaxf(ldm, __shfl_xor(ldm, off, 64));
        lsm = fmaxf(lsm, __shfl_xor(lsm, off, 64));
        ltm = fmaxf(ltm, __shfl_xor(ltm, off, 64));
    }
    if (pl == 0) { wmax[th][0] = ldm; wmax[th][1] = lsm; wmax[th][2] = ltm; }
    __syncthreads();
    if (tid == 0) {
        float m0 = 0.f, m1 = 0.f, m2 = 0.f;
#pragma unroll
        for (int i = 0; i < 16; ++i) {
            m0 = fmaxf(m0, wmax[i][0]);
            m1 = fmaxf(m1, wmax[i][1]);
            m2 = fmaxf(m2, wmax[i][2]);
        }
        float* q = pmax + (size_t)(b * NXB + bx) * 3;
        q[0] = m0; q[1] = m1; q[2] = m2;
    }
}

// ---------------- K2 (fused selection + resolution): block per (b,t) ----------------
// Phase 0: cost + S -> LDS. Phase 1 (wave 0): bottom-4 S (== top-4 liou, monotone)
// -> dynamic-k; top-4 lowest cost -> sel/selc; publish + ACQ_REL agent atomic.
// Phase 2: the 16th (last) block of each batch resolves conflicts and writes out.
__global__ __launch_bounds__(256) void k2(
        const float* __restrict__ targets, const int* __restrict__ masks,
        const int* __restrict__ imgw_p, const int* __restrict__ imgh_p,
        const float* __restrict__ Sarr,
        const float4* __restrict__ scal4, const float* __restrict__ pths,
        const float* __restrict__ pmax, const float* __restrict__ cntg,
        int* __restrict__ ctr,
        int4* __restrict__ selG, float4* __restrict__ selcG,
        int* __restrict__ out) {
    __shared__ float costL[1024];
    __shared__ float SL[1024];
    __shared__ int selEL[64];
    __shared__ float selCL[64];
    __shared__ int flagS;

    const int wid = blockIdx.x;              // (b,t)
    const int b = wid >> 4, t = wid & 15;
    const int tid = threadIdx.x;

    // per-batch maxes from the 16 partials (uniform scalar loads)
    float dm = 0.f, sm = 0.f, tm = 0.f;
    for (int i = 0; i < NXB; ++i) {
        const float* q = pmax + (size_t)(b * NXB + i) * 3;
        dm = fmaxf(dm, q[0]); sm = fmaxf(sm, q[1]); tm = fmaxf(tm, q[2]);
    }
    dm = fmaxf(dm, 1e-8f); sm = fmaxf(sm, 1e-8f); tm = fmaxf(tm, 1e-8f);

    const float w = (float)(imgw_p[0] - 1);
    const float h = (float)(imgh_p[0] - 1);
    const float* tr = targets + (size_t)(b * T_ + t) * D_;
    const float ts0 = tr[2] * h, ts1 = tr[3] * w, tth = tr[4];
    int lab = (int)tr[1]; lab = lab < 0 ? 0 : (lab > 1 ? 1 : lab);
    const int mk = masks[b * T_ + t];
    const float cntv = cntg[b * T_ + t];
    const float clen = fmaxf(cntv, 1.f);
    const float c30 = 30.f * cntv;

    const float* Srow = Sarr + (size_t)(b * T_ + t) * P_;
    const float4* s4b = scal4 + (size_t)b * P_;
    const float* ptb = pths + (size_t)b * P_;

    // ---- phase 0: cost + S -> LDS (4 p's/thread, coalesced) ----
#pragma unroll
    for (int i = 0; i < 4; ++i) {
        int p = tid + 256 * i;
        if (p < P_) {
            float S = Srow[p];
            float4 s4 = s4b[p];
            float pth = ptb[p];
            float dv = S / clen;                      // == k1's dist, bit-identical
            float dsc = 1.f - dv / dm + 0.01f;
            float d0 = s4.z - ts0, d1 = s4.w - ts1;
            float ssc = 1.f - sqrtf(d0 * d0 + d1 * d1) / sm + 0.01f;
            float tsc = 1.f - fabsf(pth - tth) * 180.f / tm + 0.01f;
            float reg = fmaxf(dsc, 1e-3f) * fmaxf(ssc, 1e-3f) * fmaxf(tsc, 1e-3f);
            float c = -(reg * reg) * 3.f + (lab ? s4.y : s4.x);
            if (mk <= 0) c = BIGC;
            costL[p] = c;
            SL[p] = S;
        } else {
            costL[p] = INFINITY;
            SL[p] = INFINITY;                          // ascending-S scan sentinel
        }
    }
    __syncthreads();

    // ---- phase 1: wave 0 scans ----
    if (tid < 64) {
        const int lane = tid;

        // bottom-4 S ascending == top-4 liou descending (liou monotone-dec in S)
        float v0, v1, v2, v3;
#define SROUND(vr) { float bv = INFINITY; int bi = 0x7fffffff;            \
        _Pragma("unroll")                                                 \
        for (int i = 0; i < 16; ++i) { int ix = lane + 64 * i;            \
            float v = SL[ix];                                             \
            if (v < bv || (v == bv && ix < bi)) { bv = v; bi = ix; } }    \
        for (int off = 32; off; off >>= 1) {                              \
            float ov = __shfl_xor(bv, off, 64);                           \
            int oi = __shfl_xor(bi, off, 64);                             \
            if (ov < bv || (ov == bv && oi < bi)) { bv = ov; bi = oi; }   \
        }                                                                 \
        vr = bv; if ((bi & 63) == lane) SL[bi] = INFINITY; }
        SROUND(v0) SROUND(v1) SROUND(v2) SROUND(v3)
#undef SROUND
        // liou of the 4 winners (same expression k1 used -> identical floats),
        // summed in descending-liou order (== ascending-S order)
        float l0 = (c30 - v0) / (c30 + v0 + 1e-9f);
        float l1 = (c30 - v1) / (c30 + v1 + 1e-9f);
        float l2 = (c30 - v2) / (c30 + v2 + 1e-9f);
        float l3 = (c30 - v3) / (c30 + v3 + 1e-9f);
        float sum = ((l0 + l1) + l2) + l3;
        int dk = 0;
        if (mk > 0) {
            dk = (int)sum;                 // trunc toward zero == astype(int32)
            if (dk < 1) dk = 1;
            if (dk > 4) dk = 4;
        }

        // top-4 lowest cost (asc, lower-p tie-break == lax.top_k stable)
        int s0, s1, s2, s3;
        float c0, c1, c2, c3;
#define CROUND(sr, cr) { float bv = INFINITY; int bi = 0x7fffffff;        \
        _Pragma("unroll")                                                 \
        for (int i = 0; i < 16; ++i) { int ix = lane + 64 * i;            \
            float v = costL[ix];                                          \
            if (v < bv || (v == bv && ix < bi)) { bv = v; bi = ix; } }    \
        for (int off = 32; off; off >>= 1) {                              \
            float ov = __shfl_xor(bv, off, 64);                           \
            int oi = __shfl_xor(bi, off, 64);                             \
            if (ov < bv || (ov == bv && oi < bi)) { bv = ov; bi = oi; }   \
        }                                                                 \
        sr = bi; cr = bv; if ((bi & 63) == lane) costL[bi] = INFINITY; }
        CROUND(s0, c0) CROUND(s1, c1) CROUND(s2, c2) CROUND(s3, c3)
#undef CROUND

        if (lane == 0) {
            selG[wid]  = make_int4(dk > 0 ? s0 : -1, dk > 1 ? s1 : -1,
                                   dk > 2 ? s2 : -1, dk > 3 ? s3 : -1);
            selcG[wid] = make_float4(c0, c1, c2, c3);
            // publish (release) + count; 16th block of batch b resolves
            int old = __hip_atomic_fetch_add(&ctr[b], 1, __ATOMIC_ACQ_REL,
                                             __HIP_MEMORY_SCOPE_AGENT);
            flagS = (old == T_ - 1) ? 1 : 0;
        }
    }
    __syncthreads();

    // ---- phase 2: last block of this batch resolves conflicts + writes out ----
    if (flagS) {
        if (tid < 64) {
            selEL[tid] = ((const int*)selG)[b * 64 + tid];
            selCL[tid] = ((const float*)selcG)[b * 64 + tid];
        }
        __syncthreads();
#pragma unroll
        for (int i = 0; i < 4; ++i) {
            int p = tid + 256 * i;
            if (p < P_) {
                int matched = -1;
                float best = INFINITY;
#pragma unroll
                for (int t2 = 0; t2 < T_; ++t2) {
#pragma unroll
                    for (int j = 0; j < 4; ++j) {
                        if (selEL[4 * t2 + j] == p) {
                            float c = selCL[4 * t2 + j];
                            if (c < best) { best = c; matched = t2; }  // strict <
                        }
                    }
                }
                out[b * P_ + p] = (matched >= 0) ? 1 : 0;
                out[B_ * P_ + b * P_ + p] = matched;
            }
        }
    }
}

extern "C" void kernel_launch(void* const* d_in, const int* in_sizes, int n_in,
                              void* d_out, int out_size, void* d_ws, size_t ws_size,
                              hipStream_t stream) {
    const float* preds   = (const float*)d_in[0];
    const float* targets = (const float*)d_in[1];
    const int*   masks   = (const int*)d_in[2];
    const int*   imgw    = (const int*)d_in[3];
    const int*   imgh    = (const int*)d_in[4];
    int* out = (int*)d_out;

    char* ws = (char*)d_ws;
    float*  Sarr  = (float*)ws;                        // [B][T][P]  2,048,000 B
    float4* scal4 = (float4*)(ws + 2048000);           // [B][P]       512,000 B
    float*  pths  = (float*)(ws + 2560000);            // [B][P]       128,000 B
    float*  pmax  = (float*)(ws + 2688000);            // [B][NXB][3]    6,144 B
    float*  cntg  = (float*)(ws + 2694144);            // [B][T]         2,048 B
    int*    ctr   = (int*)(ws + 2696192);              // [B]              128 B
    int4*   selG  = (int4*)(ws + 2696320);             // [B*T]          8,192 B
    float4* selcG = (float4*)(ws + 2704512);           // [B*T]          8,192 B

    k1<<<dim3(NXB, B_), 1024, 0, stream>>>(preds, targets, imgw, imgh,
                                           Sarr, scal4, pths, pmax, cntg, ctr);
    k2<<<B_ * T_, 256, 0, stream>>>(targets, masks, imgw, imgh, Sarr, scal4, pths,
                                    pmax, cntg, ctr, selG, selcG, out);
}

// Round 13
// 34.285 us; speedup vs baseline: 1.3055x; 1.3055x over previous
//
#include <hip/hip_runtime.h>
#include <math.h>

#define B_ 32
#define P_ 1000
#define T_ 16
#define D_ 78
#define O_ 72
#define NXB 16            // p-chunks of 64
#define BIGC 100000000.0f

// ---------------- K1: masked-L1 sums S + per-p scalars + per-block partial maxes ----------------
// Stores only S[b][t][p]; dist = S/clen and liou = (30c-S)/(30c+S+1e-9) are
// recomputed bit-identically in k2 from S + cnt.
__global__ __launch_bounds__(1024, 8) void k1(
        const float* __restrict__ preds, const float* __restrict__ targets,
        const int* __restrict__ imgw_p, const int* __restrict__ imgh_p,
        float* __restrict__ Sarr, float4* __restrict__ scal4, float* __restrict__ pths,
        float* __restrict__ pmax, float* __restrict__ cntg) {
    __shared__ float pred_s[64 * 81];
    __shared__ float2 tomg[T_ * O_];
    __shared__ float Spart[T_][4][64];
    __shared__ float wmax[16][3];
    __shared__ float cnt_s[T_], clen_s[T_], ts0_s[T_], ts1_s[T_], tth_s[T_];

    const int b = blockIdx.y, bx = blockIdx.x;
    const int p0 = bx * 64;
    const int rows = min(64, P_ - p0);
    const int tid = threadIdx.x;
    const float w = (float)(imgw_p[0] - 1);
    const float h = (float)(imgh_p[0] - 1);
    const float imgwf = (float)imgw_p[0];

    {
        const float4* gbase = (const float4*)(preds + ((size_t)b * P_ + p0) * D_);
        const int n4 = rows * D_ / 4;
        for (int i = tid; i < n4; i += 1024) {
            float4 v = gbase[i];
            int base = i * 4;
            int r = base / D_, c = base - r * D_;
#pragma unroll
            for (int k = 0; k < 4; ++k) {
                int cc = c + k, rr = r;
                if (cc >= D_) { cc -= D_; ++rr; }
                float x = (&v.x)[k];
                if (cc >= 6 || cc == 3) x *= w;
                pred_s[rr * 81 + cc] = x;
            }
        }
    }
    for (int i = tid; i < T_ * O_; i += 1024) {
        int t = i / O_, o = i - t * O_;
        float to = targets[((size_t)b * T_ + t) * D_ + 6 + o] * w;
        float m = (to >= 0.f && to < imgwf) ? 1.f : 0.f;
        tomg[((t >> 2) * O_ + o) * 4 + (t & 3)] = make_float2(to, m);
    }
    __syncthreads();
    if (tid < T_) {
        int t = tid;
        float c = 0.f;
        for (int o = 0; o < O_; ++o) c += tomg[((t >> 2) * O_ + o) * 4 + (t & 3)].y;
        cnt_s[t] = c;
        clen_s[t] = fmaxf(c, 1.f);
        const float* tr = targets + ((size_t)b * T_ + t) * D_;
        ts0_s[t] = tr[2] * h;
        ts1_s[t] = tr[3] * w;
        tth_s[t] = tr[4];
    }
    __syncthreads();

    if (bx == 0 && tid < T_) cntg[b * T_ + tid] = cnt_s[tid];

    {
        const int lane = tid & 63;
        const int wv = tid >> 6;
        const int tg = wv & 3;
        const int oq = wv >> 2;
        const float* lrow = pred_s + lane * 81;
        const float4* tg4 = (const float4*)(tomg + (size_t)tg * O_ * 4);
        const int o_lo = oq * 18;
        float S0 = 0.f, S1 = 0.f, S2 = 0.f, S3 = 0.f;
#pragma unroll
        for (int i = 0; i < 18; ++i) {
            int o = o_lo + i;
            float po = lrow[6 + o];
            float4 r0 = tg4[2 * o];
            float4 r1 = tg4[2 * o + 1];
            S0 += r0.y * fabsf(po - r0.x);
            S1 += r0.w * fabsf(po - r0.z);
            S2 += r1.y * fabsf(po - r1.x);
            S3 += r1.w * fabsf(po - r1.z);
        }
        Spart[4 * tg + 0][oq][lane] = S0;
        Spart[4 * tg + 1][oq][lane] = S1;
        Spart[4 * tg + 2][oq][lane] = S2;
        Spart[4 * tg + 3][oq][lane] = S3;
    }
    __syncthreads();

    const int th = tid >> 6, pl = tid & 63;
    const int p = p0 + pl;
    float ldm = 0.f, lsm = 0.f, ltm = 0.f;
    if (pl < rows) {
        float S = ((Spart[th][0][pl] + Spart[th][1][pl]) + Spart[th][2][pl]) + Spart[th][3][pl];
        Sarr[(size_t)(b * T_ + th) * P_ + p] = S;
        float dv = S / clen_s[th];          // needed only for the dist-max
        ldm = dv;
        const float* prow = pred_s + pl * 81;
        float ps0 = prow[2] * h, ps1 = prow[3], pth = prow[4];
        float d0 = ps0 - ts0_s[th], d1 = ps1 - ts1_s[th];
        lsm = sqrtf(d0 * d0 + d1 * d1);
        ltm = fabsf(pth - tth_s[th]) * 180.f;
        if (th == 0) {
            float fc[2];
#pragma unroll
            for (int c = 0; c < 2; ++c) {
                float x = prow[c];
                float pc = 1.f / (1.f + expf(-x));
                float neg = -logf(1.f - pc + 1e-12f) * 0.75f * pc * pc;
                float pos = -logf(pc + 1e-12f) * 0.25f * (1.f - pc) * (1.f - pc);
                fc[c] = pos - neg;
            }
            scal4[(size_t)b * P_ + p] = make_float4(fc[0], fc[1], ps0, ps1);
            pths[(size_t)b * P_ + p] = pth;
        }
    }

    for (int off = 32; off; off >>= 1) {
        ldm = fmaxf(ldm, __shfl_xor(ldm, off, 64));
        lsm = fmaxf(lsm, __shfl_xor(lsm, off, 64));
        ltm = fmaxf(ltm, __shfl_xor(ltm, off, 64));
    }
    if (pl == 0) { wmax[th][0] = ldm; wmax[th][1] = lsm; wmax[th][2] = ltm; }
    __syncthreads();
    if (tid == 0) {
        float m0 = 0.f, m1 = 0.f, m2 = 0.f;
#pragma unroll
        for (int i = 0; i < 16; ++i) {
            m0 = fmaxf(m0, wmax[i][0]);
            m1 = fmaxf(m1, wmax[i][1]);
            m2 = fmaxf(m2, wmax[i][2]);
        }
        float* q = pmax + (size_t)(b * NXB + bx) * 3;
        q[0] = m0; q[1] = m1; q[2] = m2;
    }
}

// ---------------- K2: block per (b,t) — cost+S to LDS, wave-0 LDS-scan top-4 ----------------
// No atomics, no cross-block dependencies (round 12's atomic fold caused a
// 27 ms coherence storm). Outputs only sel + selc (16 KB).
__global__ __launch_bounds__(256) void k2(
        const float* __restrict__ targets, const int* __restrict__ masks,
        const int* __restrict__ imgw_p, const int* __restrict__ imgh_p,
        const float* __restrict__ Sarr,
        const float4* __restrict__ scal4, const float* __restrict__ pths,
        const float* __restrict__ pmax, const float* __restrict__ cntg,
        int4* __restrict__ sel, float4* __restrict__ selc) {
    __shared__ float costL[1024];
    __shared__ float SL[1024];

    const int wid = blockIdx.x;              // (b,t)
    const int b = wid >> 4, t = wid & 15;
    const int tid = threadIdx.x;

    float dm = 0.f, sm = 0.f, tm = 0.f;
    for (int i = 0; i < NXB; ++i) {
        const float* q = pmax + (size_t)(b * NXB + i) * 3;
        dm = fmaxf(dm, q[0]); sm = fmaxf(sm, q[1]); tm = fmaxf(tm, q[2]);
    }
    dm = fmaxf(dm, 1e-8f); sm = fmaxf(sm, 1e-8f); tm = fmaxf(tm, 1e-8f);

    const float w = (float)(imgw_p[0] - 1);
    const float h = (float)(imgh_p[0] - 1);
    const float* tr = targets + (size_t)(b * T_ + t) * D_;
    const float ts0 = tr[2] * h, ts1 = tr[3] * w, tth = tr[4];
    int lab = (int)tr[1]; lab = lab < 0 ? 0 : (lab > 1 ? 1 : lab);
    const int mk = masks[b * T_ + t];
    const float cntv = cntg[b * T_ + t];
    const float clen = fmaxf(cntv, 1.f);
    const float c30 = 30.f * cntv;

    const float* Srow = Sarr + (size_t)(b * T_ + t) * P_;
    const float4* s4b = scal4 + (size_t)b * P_;
    const float* ptb = pths + (size_t)b * P_;

    // ---- phase 0: cost + S -> LDS (4 p's/thread, coalesced) ----
#pragma unroll
    for (int i = 0; i < 4; ++i) {
        int p = tid + 256 * i;
        if (p < P_) {
            float S = Srow[p];
            float4 s4 = s4b[p];
            float pth = ptb[p];
            float dv = S / clen;                      // == k1's dist, bit-identical
            float dsc = 1.f - dv / dm + 0.01f;
            float d0 = s4.z - ts0, d1 = s4.w - ts1;
            float ssc = 1.f - sqrtf(d0 * d0 + d1 * d1) / sm + 0.01f;
            float tsc = 1.f - fabsf(pth - tth) * 180.f / tm + 0.01f;
            float reg = fmaxf(dsc, 1e-3f) * fmaxf(ssc, 1e-3f) * fmaxf(tsc, 1e-3f);
            float c = -(reg * reg) * 3.f + (lab ? s4.y : s4.x);
            if (mk <= 0) c = BIGC;
            costL[p] = c;
            SL[p] = S;
        } else {
            costL[p] = INFINITY;
            SL[p] = INFINITY;                          // ascending-S scan sentinel
        }
    }
    __syncthreads();
    if (tid >= 64) return;                   // wave 0 finishes alone

    const int lane = tid;

    // bottom-4 S ascending == top-4 liou descending (liou monotone-dec in S)
    float v0, v1, v2, v3;
#define SROUND(vr) { float bv = INFINITY; int bi = 0x7fffffff;            \
        _Pragma("unroll")                                                 \
        for (int i = 0; i < 16; ++i) { int ix = lane + 64 * i;            \
            float v = SL[ix];                                             \
            if (v < bv || (v == bv && ix < bi)) { bv = v; bi = ix; } }    \
        for (int off = 32; off; off >>= 1) {                              \
            float ov = __shfl_xor(bv, off, 64);                           \
            int oi = __shfl_xor(bi, off, 64);                             \
            if (ov < bv || (ov == bv && oi < bi)) { bv = ov; bi = oi; }   \
        }                                                                 \
        vr = bv; if ((bi & 63) == lane) SL[bi] = INFINITY; }
    SROUND(v0) SROUND(v1) SROUND(v2) SROUND(v3)
#undef SROUND
    // liou of the 4 winners (same expression k1 used -> identical floats),
    // summed in descending-liou order (== ascending-S order)
    float l0 = (c30 - v0) / (c30 + v0 + 1e-9f);
    float l1 = (c30 - v1) / (c30 + v1 + 1e-9f);
    float l2 = (c30 - v2) / (c30 + v2 + 1e-9f);
    float l3 = (c30 - v3) / (c30 + v3 + 1e-9f);
    float sum = ((l0 + l1) + l2) + l3;
    int dk = 0;
    if (mk > 0) {
        dk = (int)sum;                 // trunc toward zero == astype(int32)
        if (dk < 1) dk = 1;
        if (dk > 4) dk = 4;
    }

    // top-4 lowest cost (asc, lower-p tie-break == lax.top_k stable)
    int s0, s1, s2, s3;
    float c0, c1, c2, c3;
#define CROUND(sr, cr) { float bv = INFINITY; int bi = 0x7fffffff;        \
        _Pragma("unroll")                                                 \
        for (int i = 0; i < 16; ++i) { int ix = lane + 64 * i;            \
            float v = costL[ix];                                          \
            if (v < bv || (v == bv && ix < bi)) { bv = v; bi = ix; } }    \
        for (int off = 32; off; off >>= 1) {                              \
            float ov = __shfl_xor(bv, off, 64);                           \
            int oi = __shfl_xor(bi, off, 64);                             \
            if (ov < bv || (ov == bv && oi < bi)) { bv = ov; bi = oi; }   \
        }                                                                 \
        sr = bi; cr = bv; if ((bi & 63) == lane) costL[bi] = INFINITY; }
    CROUND(s0, c0) CROUND(s1, c1) CROUND(s2, c2) CROUND(s3, c3)
#undef CROUND

    if (lane == 0) {
        sel[wid]  = make_int4(dk > 0 ? s0 : -1, dk > 1 ? s1 : -1,
                              dk > 2 ? s2 : -1, dk > 3 ? s3 : -1);
        selc[wid] = make_float4(c0, c1, c2, c3);
    }
}

// ---------------- K3: membership + conflict resolution from sel/selc only ----------------
__global__ __launch_bounds__(256) void k3(const int* __restrict__ sel,
                                          const float* __restrict__ selc,
                                          int* __restrict__ out) {
    __shared__ int selE[64];
    __shared__ float selC[64];
    const int b = blockIdx.y, cx = blockIdx.x;
    if (threadIdx.x < 64) {
        selE[threadIdx.x] = sel[b * 64 + threadIdx.x];
        selC[threadIdx.x] = selc[b * 64 + threadIdx.x];
    }
    __syncthreads();

    const int p = cx * 250 + threadIdx.x;
    if (threadIdx.x < 250) {
        int matched = -1;
        float best = INFINITY;
#pragma unroll
        for (int t = 0; t < T_; ++t) {
#pragma unroll
            for (int j = 0; j < 4; ++j) {
                if (selE[4 * t + j] == p) {
                    float c = selC[4 * t + j];
                    if (c < best) { best = c; matched = t; }  // strict <: first-min on t
                }
            }
        }
        out[b * P_ + p] = (matched >= 0) ? 1 : 0;
        out[B_ * P_ + b * P_ + p] = matched;
    }
}

extern "C" void kernel_launch(void* const* d_in, const int* in_sizes, int n_in,
                              void* d_out, int out_size, void* d_ws, size_t ws_size,
                              hipStream_t stream) {
    const float* preds   = (const float*)d_in[0];
    const float* targets = (const float*)d_in[1];
    const int*   masks   = (const int*)d_in[2];
    const int*   imgw    = (const int*)d_in[3];
    const int*   imgh    = (const int*)d_in[4];
    int* out = (int*)d_out;

    char* ws = (char*)d_ws;
    float*  Sarr  = (float*)ws;                        // [B][T][P]  2,048,000 B
    float4* scal4 = (float4*)(ws + 2048000);           // [B][P]       512,000 B
    float*  pths  = (float*)(ws + 2560000);            // [B][P]       128,000 B
    float*  pmax  = (float*)(ws + 2688000);            // [B][NXB][3]    6,144 B
    float*  cntg  = (float*)(ws + 2694144);            // [B][T]         2,048 B
    int4*   sel   = (int4*)(ws + 2696192);             // [B*T]          8,192 B
    float4* selc  = (float4*)(ws + 2704384);           // [B*T]          8,192 B

    k1<<<dim3(NXB, B_), 1024, 0, stream>>>(preds, targets, imgw, imgh,
                                           Sarr, scal4, pths, pmax, cntg);
    k2<<<B_ * T_, 256, 0, stream>>>(targets, masks, imgw, imgh, Sarr, scal4, pths,
                                    pmax, cntg, sel, selc);
    k3<<<dim3(4, B_), 256, 0, stream>>>((const int*)sel, (const float*)selc, out);
}